// Round 4
// baseline (335.747 us; speedup 1.0000x reference)
//
#include <hip/hip_runtime.h>

#define N_NODES 50000
#define N_EDGES 1600000
#define N_HEAD 4
#define F_OUT 128
#define CAP 96        // per-node bucket capacity; Poisson(32), P(>96) ~ 5e-14
#define NPS 512       // nodes per super-bucket
#define K1 98         // ceil(50000/512)
#define SCAP 17408    // super capacity: mean 16384 + 8 sigma(128)
#define NPG 32        // nodes per agg block (4 waves, 8 nodes per wave)
#define GROUPS 1563   // ceil(50000/32)
#define EPB 2048      // edges per partition block
#define P1_BLOCKS ((N_EDGES + EPB - 1) / EPB)   // 782
#define SCORE_BLOCKS ((N_NODES * 64 + 255) / 256)  // 12500
#define FUSED_BLOCKS (P1_BLOCKS + SCORE_BLOCKS)

// ---------------- fused K1+K2: partition blocks first (long pole), score fills in
__global__ void __launch_bounds__(256) prep_kernel(
    const float* __restrict__ x, const float* __restrict__ w,
    const float* __restrict__ a, float4* __restrict__ s_src4,
    float4* __restrict__ s_dst4,
    const int* __restrict__ src, const int* __restrict__ dst,
    int* __restrict__ gc, unsigned int* __restrict__ region) {
  __shared__ int hist[K1], cur[K1], lstart[K1], gpos[K1];
  __shared__ unsigned int staging[EPB];
  const int tid = threadIdx.x;

  if (blockIdx.x >= P1_BLOCKS) {
    // ---------------- score part ----------------
    int bid = blockIdx.x - P1_BLOCKS;
    if (bid == 0 && tid == 0) {
      // sentinel: edge-weight = exp(-inf) = 0 for padded bucket slots
      s_dst4[N_NODES] = make_float4(INFINITY, INFINITY, INFINITY, INFINITY);
    }
    int wv = (bid * 256 + tid) >> 6;
    int lane = tid & 63;
    if (wv >= N_NODES) return;
    float xv0 = x[wv * F_OUT + lane];
    float xv1 = x[wv * F_OUT + 64 + lane];
    float ps[N_HEAD], pd[N_HEAD];
#pragma unroll
    for (int h = 0; h < N_HEAD; ++h) {
      float w0 = w[h * F_OUT + lane];
      float w1 = w[h * F_OUT + 64 + lane];
      float as0 = a[h * 2 * F_OUT + lane];
      float as1 = a[h * 2 * F_OUT + 64 + lane];
      float ad0 = a[h * 2 * F_OUT + F_OUT + lane];
      float ad1 = a[h * 2 * F_OUT + F_OUT + 64 + lane];
      ps[h] = xv0 * w0 * as0 + xv1 * w1 * as1;
      pd[h] = xv0 * w0 * ad0 + xv1 * w1 * ad1;
    }
#pragma unroll
    for (int off = 32; off > 0; off >>= 1) {
#pragma unroll
      for (int h = 0; h < N_HEAD; ++h) {
        ps[h] += __shfl_xor(ps[h], off, 64);
        pd[h] += __shfl_xor(pd[h], off, 64);
      }
    }
    if (lane == 0) {
      s_src4[wv] = make_float4(ps[0], ps[1], ps[2], ps[3]);
      s_dst4[wv] = make_float4(pd[0], pd[1], pd[2], pd[3]);
    }
    return;
  }

  // ---------------- partition part ----------------
  const int base = blockIdx.x * EPB;
  int vc = N_EDGES - base;
  if (vc > EPB) vc = EPB;

  unsigned int pk[EPB / 256];
#pragma unroll
  for (int k = 0; k < EPB / 256; ++k) {
    int i = k * 256 + tid;
    if (i < vc) {
      unsigned int s = (unsigned int)src[base + i];
      unsigned int d = (unsigned int)dst[base + i];
      pk[k] = (s << 16) | d;           // valid packed can never be 0xffffffff
    } else {
      pk[k] = 0xffffffffu;
    }
  }
  if (tid < K1) { hist[tid] = 0; cur[tid] = 0; }
  __syncthreads();
#pragma unroll
  for (int k = 0; k < EPB / 256; ++k)
    if (pk[k] != 0xffffffffu) atomicAdd(&hist[pk[k] >> 25], 1);
  __syncthreads();
  // wave 0: exclusive scan of hist + global reservation
  if (tid < 64) {
    int carry = 0;
    for (int b0 = 0; b0 < K1; b0 += 64) {
      int idx = b0 + tid;
      int h = (idx < K1) ? hist[idx] : 0;
      int v = h;
#pragma unroll
      for (int off = 1; off < 64; off <<= 1) {
        int t = __shfl_up(v, off, 64);
        if (tid >= off) v += t;
      }
      if (idx < K1) {
        lstart[idx] = carry + v - h;
        gpos[idx] = atomicAdd(&gc[idx], h);
      }
      carry += __shfl(v, 63, 64);
    }
  }
  __syncthreads();
  // place into LDS staging, sorted by coarse bucket
#pragma unroll
  for (int k = 0; k < EPB / 256; ++k) {
    if (pk[k] != 0xffffffffu) {
      int b = pk[k] >> 25;
      int pos = lstart[b] + atomicAdd(&cur[b], 1);
      staging[pos] = pk[k];
    }
  }
  __syncthreads();
  // copy out: consecutive lanes -> consecutive global addresses within each run
  for (int i = tid; i < vc; i += 256) {
    unsigned int v = staging[i];
    int b = v >> 25;
    int off = gpos[b] + (i - lstart[b]);
    if (off < SCAP) region[(size_t)b * SCAP + off] = v;
  }
}

// ---------------- K3: fused bucket + single-pass gather/weight/accumulate ------
// One 256-thread block per 32-node group (16 groups per super). Per wave-node:
// ONE loop over edges: LDS idx -> {s_dst4 broadcast-gather, x-row gather} ->
// in-register weight (expf, redundant across the 32-lane half) -> FMA.
// No lds_w, no phase A/B serialization; 8 loads in flight per wave.
// Pad slots use sentinel index N_NODES whose s_dst4 = +inf => weight exactly 0.

#define SCAN_PROC(v)                                                       \
  {                                                                        \
    unsigned int s_ = (v) >> 16;                                           \
    if ((s_ >> 5) == gtag) {                                               \
      int l_ = s_ & 31;                                                    \
      int p_ = atomicAdd(&ncnt[l_], 1);                                    \
      if (p_ < CAP) nbkt[l_][p_] = (int)((v) & 0xffffu);                   \
    }                                                                      \
  }

__global__ void __launch_bounds__(256, 6) agg_kernel(
    const float* __restrict__ x, const float* __restrict__ w,
    const float4* __restrict__ s_src4, const float4* __restrict__ s_dst4,
    const int* __restrict__ gc, const unsigned int* __restrict__ region,
    float* __restrict__ out) {
  __shared__ int ncnt[NPG];
  __shared__ int nbkt[NPG][CAP];        // 12.3 KB
  const int tid = threadIdx.x;
  const int g = blockIdx.x;
  const int sb = g >> 4;                 // 16 groups per super (512/32)
  int c = gc[sb];
  if (c > SCAP) c = SCAP;
  if (tid < NPG) ncnt[tid] = 0;
  __syncthreads();

  // ---- scan super region: uint4 vector loads (region slices are 16B-aligned) --
  const unsigned int* reg = region + (size_t)sb * SCAP;
  const unsigned int gtag = (unsigned int)g;
  {
    const uint4* reg4 = (const uint4*)reg;
    int c4 = c >> 2;
    for (int i = tid; i < c4; i += 256) {
      uint4 v = reg4[i];
      SCAN_PROC(v.x); SCAN_PROC(v.y); SCAN_PROC(v.z); SCAN_PROC(v.w);
    }
    for (int i = (c4 << 2) + tid; i < c; i += 256) {
      unsigned int v = reg[i];
      SCAN_PROC(v);
    }
  }
  __syncthreads();

  const int ws = tid >> 6, lane = tid & 63;
  const int half = lane >> 5;            // 0: even edge slots, 1: odd
  const int sl = lane & 31;              // feature group: feats 4*sl..4*sl+3
  const float4* x4 = (const float4*)x;   // 32 float4 per row

  // node-invariant epilogue weights
  const float4* w4 = (const float4*)w;
  const float4 wA = w4[(half ? 1 : 0) * 32 + sl];
  const float4 wB = w4[(half ? 3 : 2) * 32 + sl];

  float4 ss = s_src4[g * NPG + ws];      // first node's scores (prefetched)

  for (int l = ws; l < NPG; l += 4) {
    int n = g * NPG + l;
    if (n >= N_NODES) break;
    // prefetch next node's scores (hidden under this node's edge loop)
    int nn = n + 4;
    if (nn > N_NODES - 1) nn = N_NODES - 1;
    float4 ss_next = s_src4[nn];

    int m = ncnt[l];
    m = (m < CAP) ? m : CAP;
    int m_pad = (m + 7) & ~7;            // <= CAP since CAP % 8 == 0
    if (lane < m_pad - m) nbkt[l][m + lane] = N_NODES;   // sentinel pad

    float4 acc0 = {0.f, 0.f, 0.f, 0.f}, acc1 = {0.f, 0.f, 0.f, 0.f};
    float4 acc2 = {0.f, 0.f, 0.f, 0.f}, acc3 = {0.f, 0.f, 0.f, 0.f};
    float p0 = 0.f, p1 = 0.f, p2 = 0.f, p3 = 0.f;

    for (int t = 0; t < m_pad; t += 8) {
      int dd[4];
      float4 sd[4], xv[4];
#pragma unroll
      for (int q = 0; q < 4; ++q) dd[q] = nbkt[l][t + 2 * q + half];
#pragma unroll
      for (int q = 0; q < 4; ++q) sd[q] = s_dst4[dd[q]];
#pragma unroll
      for (int q = 0; q < 4; ++q) {
        int dx = dd[q] < N_NODES - 1 ? dd[q] : N_NODES - 1;   // clamp sentinel
        xv[q] = x4[(size_t)dx * 32 + sl];
      }
#pragma unroll
      for (int q = 0; q < 4; ++q) {
        float s0 = ss.x + sd[q].x, s1 = ss.y + sd[q].y;
        float s2 = ss.z + sd[q].z, s3 = ss.w + sd[q].w;
        float e0 = __expf(-fmaxf(s0, 0.2f * s0));
        float e1 = __expf(-fmaxf(s1, 0.2f * s1));
        float e2 = __expf(-fmaxf(s2, 0.2f * s2));
        float e3 = __expf(-fmaxf(s3, 0.2f * s3));
        p0 += e0; p1 += e1; p2 += e2; p3 += e3;
        acc0.x = fmaf(e0, xv[q].x, acc0.x); acc0.y = fmaf(e0, xv[q].y, acc0.y);
        acc0.z = fmaf(e0, xv[q].z, acc0.z); acc0.w = fmaf(e0, xv[q].w, acc0.w);
        acc1.x = fmaf(e1, xv[q].x, acc1.x); acc1.y = fmaf(e1, xv[q].y, acc1.y);
        acc1.z = fmaf(e1, xv[q].z, acc1.z); acc1.w = fmaf(e1, xv[q].w, acc1.w);
        acc2.x = fmaf(e2, xv[q].x, acc2.x); acc2.y = fmaf(e2, xv[q].y, acc2.y);
        acc2.z = fmaf(e2, xv[q].z, acc2.z); acc2.w = fmaf(e2, xv[q].w, acc2.w);
        acc3.x = fmaf(e3, xv[q].x, acc3.x); acc3.y = fmaf(e3, xv[q].y, acc3.y);
        acc3.z = fmaf(e3, xv[q].z, acc3.z); acc3.w = fmaf(e3, xv[q].w, acc3.w);
      }
    }

    // ---- rowsums: each half holds identical per-head sums over its edges ----
    p0 += __shfl_xor(p0, 32, 64);
    p1 += __shfl_xor(p1, 32, 64);
    p2 += __shfl_xor(p2, 32, 64);
    p3 += __shfl_xor(p3, 32, 64);

    // ---- cross-half accumulator reduction ----
    acc0.x += __shfl_xor(acc0.x, 32, 64); acc0.y += __shfl_xor(acc0.y, 32, 64);
    acc0.z += __shfl_xor(acc0.z, 32, 64); acc0.w += __shfl_xor(acc0.w, 32, 64);
    acc1.x += __shfl_xor(acc1.x, 32, 64); acc1.y += __shfl_xor(acc1.y, 32, 64);
    acc1.z += __shfl_xor(acc1.z, 32, 64); acc1.w += __shfl_xor(acc1.w, 32, 64);
    acc2.x += __shfl_xor(acc2.x, 32, 64); acc2.y += __shfl_xor(acc2.y, 32, 64);
    acc2.z += __shfl_xor(acc2.z, 32, 64); acc2.w += __shfl_xor(acc2.w, 32, 64);
    acc3.x += __shfl_xor(acc3.x, 32, 64); acc3.y += __shfl_xor(acc3.y, 32, 64);
    acc3.z += __shfl_xor(acc3.z, 32, 64); acc3.w += __shfl_xor(acc3.w, 32, 64);

    float r0 = 1.f / p0, r1 = 1.f / p1, r2 = 1.f / p2, r3 = 1.f / p3;

    // ---- epilogue: lanes 0-31 write heads {0,2}, lanes 32-63 heads {1,3} ----
    float4 aA = half ? acc1 : acc0;
    float4 aB = half ? acc3 : acc2;
    float rA = half ? r1 : r0;
    float rB = half ? r3 : r2;
    float4 o;
    o.x = wA.x * aA.x * rA; o.y = wA.y * aA.y * rA;
    o.z = wA.z * aA.z * rA; o.w = wA.w * aA.w * rA;
    *(float4*)(out + ((size_t)half * N_NODES + n) * F_OUT + 4 * sl) = o;
    o.x = wB.x * aB.x * rB; o.y = wB.y * aB.y * rB;
    o.z = wB.z * aB.z * rB; o.w = wB.w * aB.w * rB;
    *(float4*)(out + ((size_t)(2 + half) * N_NODES + n) * F_OUT + 4 * sl) = o;

    ss = ss_next;
  }
}

extern "C" void kernel_launch(void* const* d_in, const int* in_sizes, int n_in,
                              void* d_out, int out_size, void* d_ws, size_t ws_size,
                              hipStream_t stream) {
  const float* x = (const float*)d_in[0];
  const float* w = (const float*)d_in[1];
  const float* a = (const float*)d_in[2];
  const int* ei = (const int*)d_in[3];
  const int* src = ei;
  const int* dst = ei + N_EDGES;
  float* out = (float*)d_out;

  char* p = (char*)d_ws;
  float4* s_src4 = (float4*)p;      p += (size_t)(N_NODES + 1) * 16;
  float4* s_dst4 = (float4*)p;      p += (size_t)(N_NODES + 1) * 16;
  int* gc = (int*)p;                p += 4096;                        // K1 counters
  unsigned int* region = (unsigned int*)p;
  p += (size_t)K1 * SCAP * 4;                                        // 6.8 MB

  hipMemsetAsync(gc, 0, 4096, stream);

  prep_kernel<<<FUSED_BLOCKS, 256, 0, stream>>>(x, w, a, s_src4, s_dst4,
                                                src, dst, gc, region);
  agg_kernel<<<GROUPS, 256, 0, stream>>>(x, w, s_src4, s_dst4, gc, region, out);
}

// Round 5
// 328.599 us; speedup vs baseline: 1.0218x; 1.0218x over previous
//
#include <hip/hip_runtime.h>

#define N_NODES 50000
#define N_EDGES 1600000
#define N_HEAD 4
#define F_OUT 128
#define CAP 96        // per-node bucket capacity; Poisson(32), P(>96) ~ 5e-14
#define NPS 512       // nodes per super-bucket
#define K1 98         // ceil(50000/512)
#define SCAP 17408    // super capacity: mean 16384 + 8 sigma(128)
#define NPG 32        // nodes per agg block (4 waves, 8 nodes per wave)
#define GROUPS 1563   // ceil(50000/32)
#define EPB 2048      // edges per partition block
#define P1_BLOCKS ((N_EDGES + EPB - 1) / EPB)   // 782
#define SCORE_BLOCKS ((N_NODES * 64 + 255) / 256)  // 12500
#define FUSED_BLOCKS (P1_BLOCKS + SCORE_BLOCKS)

// ---------------- fused K1+K2: partition blocks first (long pole), score fills in
__global__ void __launch_bounds__(256) prep_kernel(
    const float* __restrict__ x, const float* __restrict__ w,
    const float* __restrict__ a, float4* __restrict__ s_src4,
    float4* __restrict__ s_dst4,
    const int* __restrict__ src, const int* __restrict__ dst,
    int* __restrict__ gc, unsigned int* __restrict__ region) {
  __shared__ int hist[K1], cur[K1], lstart[K1], gpos[K1];
  __shared__ unsigned int staging[EPB];
  const int tid = threadIdx.x;

  if (blockIdx.x >= P1_BLOCKS) {
    // ---------------- score part ----------------
    int bid = blockIdx.x - P1_BLOCKS;
    if (bid == 0 && tid == 0) {
      // sentinel: edge-weight = exp(-inf) = 0 for padded bucket slots
      s_dst4[N_NODES] = make_float4(INFINITY, INFINITY, INFINITY, INFINITY);
    }
    int wv = (bid * 256 + tid) >> 6;
    int lane = tid & 63;
    if (wv >= N_NODES) return;
    float xv0 = x[wv * F_OUT + lane];
    float xv1 = x[wv * F_OUT + 64 + lane];
    float ps[N_HEAD], pd[N_HEAD];
#pragma unroll
    for (int h = 0; h < N_HEAD; ++h) {
      float w0 = w[h * F_OUT + lane];
      float w1 = w[h * F_OUT + 64 + lane];
      float as0 = a[h * 2 * F_OUT + lane];
      float as1 = a[h * 2 * F_OUT + 64 + lane];
      float ad0 = a[h * 2 * F_OUT + F_OUT + lane];
      float ad1 = a[h * 2 * F_OUT + F_OUT + 64 + lane];
      ps[h] = xv0 * w0 * as0 + xv1 * w1 * as1;
      pd[h] = xv0 * w0 * ad0 + xv1 * w1 * ad1;
    }
#pragma unroll
    for (int off = 32; off > 0; off >>= 1) {
#pragma unroll
      for (int h = 0; h < N_HEAD; ++h) {
        ps[h] += __shfl_xor(ps[h], off, 64);
        pd[h] += __shfl_xor(pd[h], off, 64);
      }
    }
    if (lane == 0) {
      s_src4[wv] = make_float4(ps[0], ps[1], ps[2], ps[3]);
      s_dst4[wv] = make_float4(pd[0], pd[1], pd[2], pd[3]);
    }
    return;
  }

  // ---------------- partition part ----------------
  const int base = blockIdx.x * EPB;
  int vc = N_EDGES - base;
  if (vc > EPB) vc = EPB;

  unsigned int pk[EPB / 256];
#pragma unroll
  for (int k = 0; k < EPB / 256; ++k) {
    int i = k * 256 + tid;
    if (i < vc) {
      unsigned int s = (unsigned int)src[base + i];
      unsigned int d = (unsigned int)dst[base + i];
      pk[k] = (s << 16) | d;           // valid packed can never be 0xffffffff
    } else {
      pk[k] = 0xffffffffu;
    }
  }
  if (tid < K1) { hist[tid] = 0; cur[tid] = 0; }
  __syncthreads();
#pragma unroll
  for (int k = 0; k < EPB / 256; ++k)
    if (pk[k] != 0xffffffffu) atomicAdd(&hist[pk[k] >> 25], 1);
  __syncthreads();
  // wave 0: exclusive scan of hist + global reservation
  if (tid < 64) {
    int carry = 0;
    for (int b0 = 0; b0 < K1; b0 += 64) {
      int idx = b0 + tid;
      int h = (idx < K1) ? hist[idx] : 0;
      int v = h;
#pragma unroll
      for (int off = 1; off < 64; off <<= 1) {
        int t = __shfl_up(v, off, 64);
        if (tid >= off) v += t;
      }
      if (idx < K1) {
        lstart[idx] = carry + v - h;
        gpos[idx] = atomicAdd(&gc[idx], h);
      }
      carry += __shfl(v, 63, 64);
    }
  }
  __syncthreads();
  // place into LDS staging, sorted by coarse bucket
#pragma unroll
  for (int k = 0; k < EPB / 256; ++k) {
    if (pk[k] != 0xffffffffu) {
      int b = pk[k] >> 25;
      int pos = lstart[b] + atomicAdd(&cur[b], 1);
      staging[pos] = pk[k];
    }
  }
  __syncthreads();
  // copy out: consecutive lanes -> consecutive global addresses within each run
  for (int i = tid; i < vc; i += 256) {
    unsigned int v = staging[i];
    int b = v >> 25;
    int off = gpos[b] + (i - lstart[b]);
    if (off < SCAP) region[(size_t)b * SCAP + off] = v;
  }
}

// ---------------- K3: bucket + cross-node-pipelined gather/accumulate ----------
// One 256-thread block per 32-node group. Per wave-node pipeline:
//   issue(next):  nbkt pad, s_dst4 gather + s_src4 load for node l+4 (in flight)
//   phase B(l):   2-stage pipelined x-gather + FMA (8 loads in flight)
//   finish(next): expf -> lds_w[ws][buf^1], per-lane rowsum partials
//   epilogue(l):  shfl reduces + normalized stores
// expf runs ONCE per edge (64 distinct edges per wave-instr); weights double-
// buffered per wave in LDS. Sentinel s_dst4[N_NODES]=+inf gives e=0 for pads.

#define EDGE_FMA(W, X)                                                     \
  acc0.x = fmaf(W.x, X.x, acc0.x); acc0.y = fmaf(W.x, X.y, acc0.y);        \
  acc0.z = fmaf(W.x, X.z, acc0.z); acc0.w = fmaf(W.x, X.w, acc0.w);        \
  acc1.x = fmaf(W.y, X.x, acc1.x); acc1.y = fmaf(W.y, X.y, acc1.y);        \
  acc1.z = fmaf(W.y, X.z, acc1.z); acc1.w = fmaf(W.y, X.w, acc1.w);        \
  acc2.x = fmaf(W.z, X.x, acc2.x); acc2.y = fmaf(W.z, X.y, acc2.y);        \
  acc2.z = fmaf(W.z, X.z, acc2.z); acc2.w = fmaf(W.z, X.w, acc2.w);        \
  acc3.x = fmaf(W.w, X.x, acc3.x); acc3.y = fmaf(W.w, X.y, acc3.y);        \
  acc3.z = fmaf(W.w, X.z, acc3.z); acc3.w = fmaf(W.w, X.w, acc3.w);

#define LOADB(t, D0, D1, D2, D3, X0, X1, X2, X3)                           \
  D0 = nbkt[l][(t) + half];     D1 = nbkt[l][(t) + 2 + half];              \
  D2 = nbkt[l][(t) + 4 + half]; D3 = nbkt[l][(t) + 6 + half];              \
  X0 = x4[(size_t)D0 * 32 + sl]; X1 = x4[(size_t)D1 * 32 + sl];            \
  X2 = x4[(size_t)D2 * 32 + sl]; X3 = x4[(size_t)D3 * 32 + sl];

#define FMA8(t, X0, X1, X2, X3)                                            \
  { const float4* wp = &lds_w[ws][cur][(t) + half];                        \
    float4 w0_ = wp[0], w1_ = wp[2], w2_ = wp[4], w3_ = wp[6];             \
    EDGE_FMA(w0_, X0) EDGE_FMA(w1_, X1) EDGE_FMA(w2_, X2) EDGE_FMA(w3_, X3) }

#define SCAN_PROC(v)                                                       \
  {                                                                        \
    unsigned int s_ = (v) >> 16;                                           \
    if ((s_ >> 5) == gtag) {                                               \
      int l_ = s_ & 31;                                                    \
      int p_ = atomicAdd(&ncnt[l_], 1);                                    \
      if (p_ < CAP) nbkt[l_][p_] = (int)((v) & 0xffffu);                   \
    }                                                                      \
  }

__global__ void __launch_bounds__(256, 4) agg_kernel(
    const float* __restrict__ x, const float* __restrict__ w,
    const float4* __restrict__ s_src4, const float4* __restrict__ s_dst4,
    const int* __restrict__ gc, const unsigned int* __restrict__ region,
    float* __restrict__ out) {
  __shared__ int ncnt[NPG];
  __shared__ int nbkt[NPG][CAP];        // 12.3 KB
  __shared__ float4 lds_w[4][2][CAP];   // 12.3 KB, wave-private double buffer
  const int tid = threadIdx.x;
  const int g = blockIdx.x;
  const int sb = g >> 4;                 // 16 groups per super (512/32)
  int c = gc[sb];
  if (c > SCAP) c = SCAP;
  if (tid < NPG) ncnt[tid] = 0;
  __syncthreads();

  // ---- scan super region: uint4 vector loads ----
  const unsigned int* reg = region + (size_t)sb * SCAP;
  const unsigned int gtag = (unsigned int)g;
  {
    const uint4* reg4 = (const uint4*)reg;
    int c4 = c >> 2;
    for (int i = tid; i < c4; i += 256) {
      uint4 v = reg4[i];
      SCAN_PROC(v.x); SCAN_PROC(v.y); SCAN_PROC(v.z); SCAN_PROC(v.w);
    }
    for (int i = (c4 << 2) + tid; i < c; i += 256) {
      unsigned int v = reg[i];
      SCAN_PROC(v);
    }
  }
  __syncthreads();

  const int ws = tid >> 6, lane = tid & 63;
  const int half = lane >> 5;            // 0: even edge slots, 1: odd
  const int sl = lane & 31;              // feature group: feats 4*sl..4*sl+3
  const float4* x4 = (const float4*)x;   // 32 float4 per row

  // node-invariant epilogue weights
  const float4* w4 = (const float4*)w;
  const float4 wA = w4[(half ? 1 : 0) * 32 + sl];
  const float4 wB = w4[(half ? 3 : 2) * 32 + sl];

  // ---- prologue: phase A for node l = ws into buffer 0 ----
  int mp;                                // padded edge count of current node
  float pl0, pl1, pl2, pl3;              // per-lane rowsum partials (1 edge/lane)
  {
    int l = ws;
    int m = ncnt[l];
    m = (m < CAP) ? m : CAP;
    mp = (m + 7) & ~7;
    if (lane < mp - m) nbkt[l][m + lane] = 0;
    int d = (lane < m) ? nbkt[l][lane] : N_NODES;
    float4 sd = s_dst4[d];
    float4 ssc = s_src4[g * NPG + l];
    float s0 = ssc.x + sd.x, s1 = ssc.y + sd.y;
    float s2 = ssc.z + sd.z, s3 = ssc.w + sd.w;
    float e0 = __expf(-fmaxf(s0, 0.2f * s0));
    float e1 = __expf(-fmaxf(s1, 0.2f * s1));
    float e2 = __expf(-fmaxf(s2, 0.2f * s2));
    float e3 = __expf(-fmaxf(s3, 0.2f * s3));
    lds_w[ws][0][lane] = make_float4(e0, e1, e2, e3);
    pl0 = e0; pl1 = e1; pl2 = e2; pl3 = e3;
    if (m > 64) {
      for (int j = 64 + lane; j < m; j += 64) {
        int dj = nbkt[l][j];
        float4 sdj = s_dst4[dj];
        float t0 = ssc.x + sdj.x, t1 = ssc.y + sdj.y;
        float t2 = ssc.z + sdj.z, t3 = ssc.w + sdj.w;
        float f0 = __expf(-fmaxf(t0, 0.2f * t0));
        float f1 = __expf(-fmaxf(t1, 0.2f * t1));
        float f2 = __expf(-fmaxf(t2, 0.2f * t2));
        float f3 = __expf(-fmaxf(t3, 0.2f * t3));
        lds_w[ws][0][j] = make_float4(f0, f1, f2, f3);
        pl0 += f0; pl1 += f1; pl2 += f2; pl3 += f3;
      }
      if (lane < mp - m) lds_w[ws][0][m + lane] = make_float4(0.f, 0.f, 0.f, 0.f);
    }
  }
  int cur = 0;

  for (int l = ws; l < NPG; l += 4) {
    int n = g * NPG + l;
    if (n >= N_NODES) break;
    const int lnext = l + 4;
    const int nnext = g * NPG + lnext;
    const bool have_next = (lnext < NPG) && (nnext < N_NODES);

    // ---- issue next node's phase A loads (in flight during phase B) ----
    int mn = 0, mpn = 0;
    float4 sdn, ssn;
    if (have_next) {
      mn = ncnt[lnext];
      mn = (mn < CAP) ? mn : CAP;
      mpn = (mn + 7) & ~7;
      if (lane < mpn - mn) nbkt[lnext][mn + lane] = 0;
      int dn = (lane < mn) ? nbkt[lnext][lane] : N_NODES;
      sdn = s_dst4[dn];
      ssn = s_src4[nnext];
    }

    // ---- phase B: 2-stage pipelined paired gather + FMA ----
    float4 acc0 = {0.f, 0.f, 0.f, 0.f}, acc1 = {0.f, 0.f, 0.f, 0.f};
    float4 acc2 = {0.f, 0.f, 0.f, 0.f}, acc3 = {0.f, 0.f, 0.f, 0.f};
    if (mp > 0) {
      int da0, da1, da2, da3, db0, db1, db2, db3;
      float4 xa0, xa1, xa2, xa3, xb0, xb1, xb2, xb3;
      LOADB(0, da0, da1, da2, da3, xa0, xa1, xa2, xa3)
      int tB = 0;
      for (;;) {
        if (tB + 8 >= mp) { FMA8(tB, xa0, xa1, xa2, xa3) break; }
        LOADB(tB + 8, db0, db1, db2, db3, xb0, xb1, xb2, xb3)
        FMA8(tB, xa0, xa1, xa2, xa3)
        tB += 8;
        if (tB + 8 >= mp) { FMA8(tB, xb0, xb1, xb2, xb3) break; }
        LOADB(tB + 8, da0, da1, da2, da3, xa0, xa1, xa2, xa3)
        FMA8(tB, xb0, xb1, xb2, xb3)
        tB += 8;
      }
    }

    // ---- finish next node's phase A: expf once per edge -> other buffer ----
    float pn0 = 0.f, pn1 = 0.f, pn2 = 0.f, pn3 = 0.f;
    if (have_next) {
      float s0 = ssn.x + sdn.x, s1 = ssn.y + sdn.y;
      float s2 = ssn.z + sdn.z, s3 = ssn.w + sdn.w;
      float e0 = __expf(-fmaxf(s0, 0.2f * s0));
      float e1 = __expf(-fmaxf(s1, 0.2f * s1));
      float e2 = __expf(-fmaxf(s2, 0.2f * s2));
      float e3 = __expf(-fmaxf(s3, 0.2f * s3));
      lds_w[ws][cur ^ 1][lane] = make_float4(e0, e1, e2, e3);
      pn0 = e0; pn1 = e1; pn2 = e2; pn3 = e3;
      if (mn > 64) {
        for (int j = 64 + lane; j < mn; j += 64) {
          int dj = nbkt[lnext][j];
          float4 sdj = s_dst4[dj];
          float t0 = ssn.x + sdj.x, t1 = ssn.y + sdj.y;
          float t2 = ssn.z + sdj.z, t3 = ssn.w + sdj.w;
          float f0 = __expf(-fmaxf(t0, 0.2f * t0));
          float f1 = __expf(-fmaxf(t1, 0.2f * t1));
          float f2 = __expf(-fmaxf(t2, 0.2f * t2));
          float f3 = __expf(-fmaxf(t3, 0.2f * t3));
          lds_w[ws][cur ^ 1][j] = make_float4(f0, f1, f2, f3);
          pn0 += f0; pn1 += f1; pn2 += f2; pn3 += f3;
        }
        if (lane < mpn - mn)
          lds_w[ws][cur ^ 1][mn + lane] = make_float4(0.f, 0.f, 0.f, 0.f);
      }
    }

    // ---- epilogue node l: rowsum reduce (per-lane partials, full wave) ----
#pragma unroll
    for (int off = 32; off > 0; off >>= 1) {
      pl0 += __shfl_xor(pl0, off, 64);
      pl1 += __shfl_xor(pl1, off, 64);
      pl2 += __shfl_xor(pl2, off, 64);
      pl3 += __shfl_xor(pl3, off, 64);
    }
    float r0 = 1.f / pl0, r1 = 1.f / pl1, r2 = 1.f / pl2, r3 = 1.f / pl3;

    // cross-half accumulator reduction
    acc0.x += __shfl_xor(acc0.x, 32, 64); acc0.y += __shfl_xor(acc0.y, 32, 64);
    acc0.z += __shfl_xor(acc0.z, 32, 64); acc0.w += __shfl_xor(acc0.w, 32, 64);
    acc1.x += __shfl_xor(acc1.x, 32, 64); acc1.y += __shfl_xor(acc1.y, 32, 64);
    acc1.z += __shfl_xor(acc1.z, 32, 64); acc1.w += __shfl_xor(acc1.w, 32, 64);
    acc2.x += __shfl_xor(acc2.x, 32, 64); acc2.y += __shfl_xor(acc2.y, 32, 64);
    acc2.z += __shfl_xor(acc2.z, 32, 64); acc2.w += __shfl_xor(acc2.w, 32, 64);
    acc3.x += __shfl_xor(acc3.x, 32, 64); acc3.y += __shfl_xor(acc3.y, 32, 64);
    acc3.z += __shfl_xor(acc3.z, 32, 64); acc3.w += __shfl_xor(acc3.w, 32, 64);

    // lanes 0-31 write heads {0,2}, lanes 32-63 heads {1,3}
    float4 aA = half ? acc1 : acc0;
    float4 aB = half ? acc3 : acc2;
    float rA = half ? r1 : r0;
    float rB = half ? r3 : r2;
    float4 o;
    o.x = wA.x * aA.x * rA; o.y = wA.y * aA.y * rA;
    o.z = wA.z * aA.z * rA; o.w = wA.w * aA.w * rA;
    *(float4*)(out + ((size_t)half * N_NODES + n) * F_OUT + 4 * sl) = o;
    o.x = wB.x * aB.x * rB; o.y = wB.y * aB.y * rB;
    o.z = wB.z * aB.z * rB; o.w = wB.w * aB.w * rB;
    *(float4*)(out + ((size_t)(2 + half) * N_NODES + n) * F_OUT + 4 * sl) = o;

    // rotate pipeline state
    pl0 = pn0; pl1 = pn1; pl2 = pn2; pl3 = pn3;
    mp = mpn;
    cur ^= 1;
  }
}

extern "C" void kernel_launch(void* const* d_in, const int* in_sizes, int n_in,
                              void* d_out, int out_size, void* d_ws, size_t ws_size,
                              hipStream_t stream) {
  const float* x = (const float*)d_in[0];
  const float* w = (const float*)d_in[1];
  const float* a = (const float*)d_in[2];
  const int* ei = (const int*)d_in[3];
  const int* src = ei;
  const int* dst = ei + N_EDGES;
  float* out = (float*)d_out;

  char* p = (char*)d_ws;
  float4* s_src4 = (float4*)p;      p += (size_t)(N_NODES + 1) * 16;
  float4* s_dst4 = (float4*)p;      p += (size_t)(N_NODES + 1) * 16;
  int* gc = (int*)p;                p += 4096;                        // K1 counters
  unsigned int* region = (unsigned int*)p;
  p += (size_t)K1 * SCAP * 4;                                        // 6.8 MB

  hipMemsetAsync(gc, 0, 4096, stream);

  prep_kernel<<<FUSED_BLOCKS, 256, 0, stream>>>(x, w, a, s_src4, s_dst4,
                                                src, dst, gc, region);
  agg_kernel<<<GROUPS, 256, 0, stream>>>(x, w, s_src4, s_dst4, gc, region, out);
}

// Round 6
// 296.781 us; speedup vs baseline: 1.1313x; 1.1072x over previous
//
#include <hip/hip_runtime.h>

#define N_NODES 50000
#define N_EDGES 1600000
#define N_HEAD 4
#define F_OUT 128
#define CAP 96        // per-node bucket capacity; Poisson(32), P(>96) ~ 5e-14
#define NPS 512       // nodes per super-bucket
#define K1 98         // ceil(50000/512)
#define SCAP 17408    // super capacity: mean 16384 + 8 sigma(128)
#define NPG 32        // nodes per agg block (4 waves, 8 nodes per wave)
#define GROUPS 1563   // ceil(50000/32)
#define EPB 2048      // edges per partition block
#define P1_BLOCKS ((N_EDGES + EPB - 1) / EPB)   // 782
#define SCORE_BLOCKS ((N_NODES * 64 + 255) / 256)  // 12500
#define FUSED_BLOCKS (P1_BLOCKS + SCORE_BLOCKS)

// ---------------- fused K1+K2: partition blocks first (long pole), score fills in
__global__ void __launch_bounds__(256) prep_kernel(
    const float* __restrict__ x, const float* __restrict__ w,
    const float* __restrict__ a, float4* __restrict__ s_src4,
    float4* __restrict__ s_dst4,
    const int* __restrict__ src, const int* __restrict__ dst,
    int* __restrict__ gc, unsigned int* __restrict__ region) {
  __shared__ int hist[K1], cur[K1], lstart[K1], gpos[K1];
  __shared__ unsigned int staging[EPB];
  const int tid = threadIdx.x;

  if (blockIdx.x >= P1_BLOCKS) {
    // ---------------- score part ----------------
    int bid = blockIdx.x - P1_BLOCKS;
    int wv = (bid * 256 + tid) >> 6;
    int lane = tid & 63;
    if (wv >= N_NODES) return;
    float xv0 = x[wv * F_OUT + lane];
    float xv1 = x[wv * F_OUT + 64 + lane];
    float ps[N_HEAD], pd[N_HEAD];
#pragma unroll
    for (int h = 0; h < N_HEAD; ++h) {
      float w0 = w[h * F_OUT + lane];
      float w1 = w[h * F_OUT + 64 + lane];
      float as0 = a[h * 2 * F_OUT + lane];
      float as1 = a[h * 2 * F_OUT + 64 + lane];
      float ad0 = a[h * 2 * F_OUT + F_OUT + lane];
      float ad1 = a[h * 2 * F_OUT + F_OUT + 64 + lane];
      ps[h] = xv0 * w0 * as0 + xv1 * w1 * as1;
      pd[h] = xv0 * w0 * ad0 + xv1 * w1 * ad1;
    }
#pragma unroll
    for (int off = 32; off > 0; off >>= 1) {
#pragma unroll
      for (int h = 0; h < N_HEAD; ++h) {
        ps[h] += __shfl_xor(ps[h], off, 64);
        pd[h] += __shfl_xor(pd[h], off, 64);
      }
    }
    if (lane == 0) {
      s_src4[wv] = make_float4(ps[0], ps[1], ps[2], ps[3]);
      s_dst4[wv] = make_float4(pd[0], pd[1], pd[2], pd[3]);
    }
    return;
  }

  // ---------------- partition part ----------------
  const int base = blockIdx.x * EPB;
  int vc = N_EDGES - base;
  if (vc > EPB) vc = EPB;

  unsigned int pk[EPB / 256];
#pragma unroll
  for (int k = 0; k < EPB / 256; ++k) {
    int i = k * 256 + tid;
    if (i < vc) {
      unsigned int s = (unsigned int)src[base + i];
      unsigned int d = (unsigned int)dst[base + i];
      pk[k] = (s << 16) | d;           // valid packed can never be 0xffffffff
    } else {
      pk[k] = 0xffffffffu;
    }
  }
  if (tid < K1) { hist[tid] = 0; cur[tid] = 0; }
  __syncthreads();
#pragma unroll
  for (int k = 0; k < EPB / 256; ++k)
    if (pk[k] != 0xffffffffu) atomicAdd(&hist[pk[k] >> 25], 1);
  __syncthreads();
  // wave 0: exclusive scan of hist + global reservation
  if (tid < 64) {
    int carry = 0;
    for (int b0 = 0; b0 < K1; b0 += 64) {
      int idx = b0 + tid;
      int h = (idx < K1) ? hist[idx] : 0;
      int v = h;
#pragma unroll
      for (int off = 1; off < 64; off <<= 1) {
        int t = __shfl_up(v, off, 64);
        if (tid >= off) v += t;
      }
      if (idx < K1) {
        lstart[idx] = carry + v - h;
        gpos[idx] = atomicAdd(&gc[idx], h);
      }
      carry += __shfl(v, 63, 64);
    }
  }
  __syncthreads();
  // place into LDS staging, sorted by coarse bucket
#pragma unroll
  for (int k = 0; k < EPB / 256; ++k) {
    if (pk[k] != 0xffffffffu) {
      int b = pk[k] >> 25;
      int pos = lstart[b] + atomicAdd(&cur[b], 1);
      staging[pos] = pk[k];
    }
  }
  __syncthreads();
  // copy out: consecutive lanes -> consecutive global addresses within each run
  for (int i = tid; i < vc; i += 256) {
    unsigned int v = staging[i];
    int b = v >> 25;
    int off = gpos[b] + (i - lstart[b]);
    if (off < SCAP) region[(size_t)b * SCAP + off] = v;
  }
}

// ---------------- K3: fused LDS-bucket + gather/accumulate (R3 structure) ------
// One 256-thread block per 32-node group; wave-per-node phase A (expf weights
// into wave-private LDS) / phase B (paired x-gather + FMA). Phase B batch = 16
// edges: 8 dwordx4 (8 KB) in flight per wave -> half the stall windows of the
// 8-edge version. Buckets padded to x16 with zero-weight dummy edges (row 0).

#define EDGE_FMA(W, X)                                                     \
  acc0.x = fmaf(W.x, X.x, acc0.x); acc0.y = fmaf(W.x, X.y, acc0.y);        \
  acc0.z = fmaf(W.x, X.z, acc0.z); acc0.w = fmaf(W.x, X.w, acc0.w);        \
  acc1.x = fmaf(W.y, X.x, acc1.x); acc1.y = fmaf(W.y, X.y, acc1.y);        \
  acc1.z = fmaf(W.y, X.z, acc1.z); acc1.w = fmaf(W.y, X.w, acc1.w);        \
  acc2.x = fmaf(W.z, X.x, acc2.x); acc2.y = fmaf(W.z, X.y, acc2.y);        \
  acc2.z = fmaf(W.z, X.z, acc2.z); acc2.w = fmaf(W.z, X.w, acc2.w);        \
  acc3.x = fmaf(W.w, X.x, acc3.x); acc3.y = fmaf(W.w, X.y, acc3.y);        \
  acc3.z = fmaf(W.w, X.z, acc3.z); acc3.w = fmaf(W.w, X.w, acc3.w);

#define SCAN_PROC(v)                                                       \
  {                                                                        \
    unsigned int s_ = (v) >> 16;                                           \
    if ((s_ >> 5) == gtag) {                                               \
      int l_ = s_ & 31;                                                    \
      int p_ = atomicAdd(&ncnt[l_], 1);                                    \
      if (p_ < CAP) nbkt[l_][p_] = (int)((v) & 0xffffu);                   \
    }                                                                      \
  }

__global__ void __launch_bounds__(256, 4) agg_kernel(
    const float* __restrict__ x, const float* __restrict__ w,
    const float4* __restrict__ s_src4, const float4* __restrict__ s_dst4,
    const int* __restrict__ gc, const unsigned int* __restrict__ region,
    float* __restrict__ out) {
  __shared__ int ncnt[NPG];
  __shared__ int nbkt[NPG][CAP];        // 12.3 KB
  __shared__ float4 lds_w[4][CAP];      // 6.1 KB, wave-private
  const int tid = threadIdx.x;
  const int g = blockIdx.x;
  const int sb = g >> 4;                 // 16 groups per super (512/32)
  int c = gc[sb];
  if (c > SCAP) c = SCAP;
  if (tid < NPG) ncnt[tid] = 0;
  __syncthreads();

  // ---- scan super region: uint4 vector loads ----
  const unsigned int* reg = region + (size_t)sb * SCAP;
  const unsigned int gtag = (unsigned int)g;
  {
    const uint4* reg4 = (const uint4*)reg;
    int c4 = c >> 2;
    for (int i = tid; i < c4; i += 256) {
      uint4 v = reg4[i];
      SCAN_PROC(v.x); SCAN_PROC(v.y); SCAN_PROC(v.z); SCAN_PROC(v.w);
    }
    for (int i = (c4 << 2) + tid; i < c; i += 256) {
      unsigned int v = reg[i];
      SCAN_PROC(v);
    }
  }
  __syncthreads();

  const int ws = tid >> 6, lane = tid & 63;
  const int half = lane >> 5;            // 0: even edge slots, 1: odd
  const int sl = lane & 31;              // feature group: feats 4*sl..4*sl+3
  const float4* x4 = (const float4*)x;   // 32 float4 per row

  // node-invariant epilogue weights
  const float4* w4 = (const float4*)w;
  const float4 wA = w4[(half ? 1 : 0) * 32 + sl];
  const float4 wB = w4[(half ? 3 : 2) * 32 + sl];

  for (int l = ws; l < NPG; l += 4) {
    int n = g * NPG + l;
    if (n >= N_NODES) break;
    int m = ncnt[l];
    m = (m < CAP) ? m : CAP;
    float4 ss = s_src4[n];

    // ---- Phase A: edge weights into wave-private LDS, per-lane partial sums ----
    float p0 = 0.f, p1 = 0.f, p2 = 0.f, p3 = 0.f;
    for (int j = lane; j < m; j += 64) {
      int d = nbkt[l][j];
      float4 sd = s_dst4[d];
      float sc0 = ss.x + sd.x, sc1 = ss.y + sd.y, sc2 = ss.z + sd.z, sc3 = ss.w + sd.w;
      float e0 = __expf(-fmaxf(sc0, 0.2f * sc0));
      float e1 = __expf(-fmaxf(sc1, 0.2f * sc1));
      float e2 = __expf(-fmaxf(sc2, 0.2f * sc2));
      float e3 = __expf(-fmaxf(sc3, 0.2f * sc3));
      lds_w[ws][j] = make_float4(e0, e1, e2, e3);
      p0 += e0; p1 += e1; p2 += e2; p3 += e3;
    }
    // pad bucket to multiple of 16 with zero-weight dummy edges (row 0)
    int m_pad = (m + 15) & ~15;          // <= CAP since CAP % 16 == 0
    if (lane < m_pad - m) {
      nbkt[l][m + lane] = 0;
      lds_w[ws][m + lane] = make_float4(0.f, 0.f, 0.f, 0.f);
    }

    // ---- Phase B: paired gather, 8 dwordx4 (16 edges, 8KB) in flight ----
    float4 acc0 = {0.f, 0.f, 0.f, 0.f}, acc1 = {0.f, 0.f, 0.f, 0.f};
    float4 acc2 = {0.f, 0.f, 0.f, 0.f}, acc3 = {0.f, 0.f, 0.f, 0.f};
    for (int t = 0; t < m_pad; t += 16) {
      int dd[8];
      float4 xv[8], wv[8];
#pragma unroll
      for (int q = 0; q < 8; ++q) dd[q] = nbkt[l][t + 2 * q + half];
#pragma unroll
      for (int q = 0; q < 8; ++q) xv[q] = x4[(size_t)dd[q] * 32 + sl];
#pragma unroll
      for (int q = 0; q < 8; ++q) wv[q] = lds_w[ws][t + 2 * q + half];
#pragma unroll
      for (int q = 0; q < 8; ++q) { EDGE_FMA(wv[q], xv[q]) }
    }

    // ---- cross-half reduction (even-edge + odd-edge partials) ----
    acc0.x += __shfl_xor(acc0.x, 32, 64); acc0.y += __shfl_xor(acc0.y, 32, 64);
    acc0.z += __shfl_xor(acc0.z, 32, 64); acc0.w += __shfl_xor(acc0.w, 32, 64);
    acc1.x += __shfl_xor(acc1.x, 32, 64); acc1.y += __shfl_xor(acc1.y, 32, 64);
    acc1.z += __shfl_xor(acc1.z, 32, 64); acc1.w += __shfl_xor(acc1.w, 32, 64);
    acc2.x += __shfl_xor(acc2.x, 32, 64); acc2.y += __shfl_xor(acc2.y, 32, 64);
    acc2.z += __shfl_xor(acc2.z, 32, 64); acc2.w += __shfl_xor(acc2.w, 32, 64);
    acc3.x += __shfl_xor(acc3.x, 32, 64); acc3.y += __shfl_xor(acc3.y, 32, 64);
    acc3.z += __shfl_xor(acc3.z, 32, 64); acc3.w += __shfl_xor(acc3.w, 32, 64);

    // ---- rowsum reduction (phase A partials live across all 64 lanes) ----
#pragma unroll
    for (int off = 32; off > 0; off >>= 1) {
      p0 += __shfl_xor(p0, off, 64);
      p1 += __shfl_xor(p1, off, 64);
      p2 += __shfl_xor(p2, off, 64);
      p3 += __shfl_xor(p3, off, 64);
    }
    float r0 = 1.f / p0, r1 = 1.f / p1, r2 = 1.f / p2, r3 = 1.f / p3;

    // ---- epilogue: lanes 0-31 write heads {0,2}, lanes 32-63 heads {1,3} ----
    float4 aA = half ? acc1 : acc0;
    float4 aB = half ? acc3 : acc2;
    float rA = half ? r1 : r0;
    float rB = half ? r3 : r2;
    float4 o;
    o.x = wA.x * aA.x * rA; o.y = wA.y * aA.y * rA;
    o.z = wA.z * aA.z * rA; o.w = wA.w * aA.w * rA;
    *(float4*)(out + ((size_t)half * N_NODES + n) * F_OUT + 4 * sl) = o;
    o.x = wB.x * aB.x * rB; o.y = wB.y * aB.y * rB;
    o.z = wB.z * aB.z * rB; o.w = wB.w * aB.w * rB;
    *(float4*)(out + ((size_t)(2 + half) * N_NODES + n) * F_OUT + 4 * sl) = o;
  }
}

extern "C" void kernel_launch(void* const* d_in, const int* in_sizes, int n_in,
                              void* d_out, int out_size, void* d_ws, size_t ws_size,
                              hipStream_t stream) {
  const float* x = (const float*)d_in[0];
  const float* w = (const float*)d_in[1];
  const float* a = (const float*)d_in[2];
  const int* ei = (const int*)d_in[3];
  const int* src = ei;
  const int* dst = ei + N_EDGES;
  float* out = (float*)d_out;

  char* p = (char*)d_ws;
  float4* s_src4 = (float4*)p;      p += (size_t)(N_NODES + 1) * 16;
  float4* s_dst4 = (float4*)p;      p += (size_t)(N_NODES + 1) * 16;
  int* gc = (int*)p;                p += 4096;                        // K1 counters
  unsigned int* region = (unsigned int*)p;
  p += (size_t)K1 * SCAP * 4;                                        // 6.8 MB

  hipMemsetAsync(gc, 0, 4096, stream);

  prep_kernel<<<FUSED_BLOCKS, 256, 0, stream>>>(x, w, a, s_src4, s_dst4,
                                                src, dst, gc, region);
  agg_kernel<<<GROUPS, 256, 0, stream>>>(x, w, s_src4, s_dst4, gc, region, out);
}